// Round 18
// baseline (234.887 us; speedup 1.0000x reference)
//
#include <hip/hip_runtime.h>
#include <hip/hip_bf16.h>
#include <math.h>

// BinaryTreeLSTM — round 18: gemm_gx re-geometried to 256x256 / 8 waves
// (wave tile 128x64 -> 0.375 LDS-reads per MFMA vs 0.5 at 64x64), BK=64,
// both-sides swizzle, double-buffered (128KB) with counted vmcnt(8).
// fused_level and prep unchanged (r16-proven) for clean attribution.
//
// Packed gate-interleaved column space: e = (j/16)*64 + g*16 + (j%16)
//   (orig W row g*2048+j). Wih_p[4096][1024], Whh_p[4096][2048] bf16.
// GX[4096][4096] fp16: rows 0..2046 = bf16(emb[node]) @ Wih_p^T + bge;
//   rows >= 2047 (level-11) consumed in-register by the gemm_gx epilogue.
// Hcat: level-k h-slab at row OFF(k)=4096-2^(k+1), 2^k rows x 2048 bf16.
// c compact: level k writes even-node c at row m>>1 (1024 f32); k-1 reads row m.

#define TREE_DEPTH 12

typedef unsigned short u16;
typedef unsigned int u32;
typedef __attribute__((ext_vector_type(8))) short bf16x8;
typedef __attribute__((ext_vector_type(4))) float f32x4;
typedef __attribute__((ext_vector_type(8))) unsigned short u16x8;
typedef __attribute__((ext_vector_type(2))) unsigned int u32x2;

__device__ __forceinline__ void gload16(const void* g, void* l) {
    __builtin_amdgcn_global_load_lds(
        (const __attribute__((address_space(1))) u32*)g,
        (__attribute__((address_space(3))) u32*)l, 16, 0, 0);
}

template <int N>
__device__ __forceinline__ void vmwait() {
    asm volatile("s_waitcnt vmcnt(%0)" :: "n"(N) : "memory");
}
__device__ __forceinline__ void rbar() {
    __builtin_amdgcn_sched_barrier(0);
    __builtin_amdgcn_s_barrier();
    __builtin_amdgcn_sched_barrier(0);
}

__device__ __forceinline__ u16 f2bf(float f) {
    __hip_bfloat16 h = __float2bfloat16(f);
    return *reinterpret_cast<u16*>(&h);
}
__device__ __forceinline__ u16 f2h(float f) {
    _Float16 h = (_Float16)f;
    return *reinterpret_cast<u16*>(&h);
}
__device__ __forceinline__ float h2f(u16 u) {
    _Float16 h;
    *reinterpret_cast<u16*>(&h) = u;
    return (float)h;
}
__device__ __forceinline__ float fsig(float x) {
    return 1.0f / (1.0f + __expf(-x));
}
__device__ __forceinline__ float ftanh(float x) {
    return 1.0f - 2.0f / (1.0f + __expf(2.0f * x));
}

// ---------------------------------------------------------------- prep
__global__ void prep(const float* __restrict__ Wih,
                     const float* __restrict__ Whh,
                     const float* __restrict__ emb,
                     const float* __restrict__ b_ih,
                     const float* __restrict__ b_hh,
                     u16* __restrict__ Wih_p, u16* __restrict__ Whh_p,
                     u16* __restrict__ xb, float* __restrict__ bge) {
    const int bid = blockIdx.x;
    if (bid < 12288) {
        const int b = bid & 4095;
        const int seg = bid >> 12;         // 0: ih, 1/2: hh halves
        const int x = b & 7, t = b >> 3;   // t in [0,512)
        const int e = ((t & 3) * 8 + x) * 128 + (t >> 2);  // (e>>7)%8 == x
        const int g = (e >> 4) & 3;
        const int j = (e >> 6) * 16 + (e & 15);
        const int wr = g * 2048 + j;
        const int col = threadIdx.x * 4;
        f32x4 v;
        u16* dst;
        if (seg == 0) {
            v = __builtin_nontemporal_load(
                (const f32x4*)(Wih + (size_t)wr * 1024 + col));
            dst = Wih_p + (size_t)e * 1024 + col;
        } else {
            v = __builtin_nontemporal_load(
                (const f32x4*)(Whh + (size_t)wr * 2048 + (seg - 1) * 1024 + col));
            dst = Whh_p + (size_t)e * 2048 + (seg - 1) * 1024 + col;
        }
        u32x2 p;
        p[0] = (u32)f2bf(v[0]) | ((u32)f2bf(v[1]) << 16);
        p[1] = (u32)f2bf(v[2]) | ((u32)f2bf(v[3]) << 16);
        *reinterpret_cast<u32x2*>(dst) = p;
    } else if (bid < 16383) {
        size_t idx = ((size_t)(bid - 12288) * 256 + threadIdx.x) * 4;
        f32x4 v = __builtin_nontemporal_load((const f32x4*)(emb + idx));
        u32x2 p;
        p[0] = (u32)f2bf(v[0]) | ((u32)f2bf(v[1]) << 16);
        p[1] = (u32)f2bf(v[2]) | ((u32)f2bf(v[3]) << 16);
        *reinterpret_cast<u32x2*>(xb + idx) = p;
    } else {
        int e = (bid - 16383) * 256 + threadIdx.x;   // 0..4095 packed order
        int g = (e >> 4) & 3;
        int j = (e >> 6) * 16 + (e & 15);
        int r = g * 2048 + j;
        bge[e] = b_ih[r] + b_hh[r];
    }
}

// ---------------------------------------------------------------- GX GEMM
// 256x256 tile, 8 waves (wm 0..1 x wn 0..3, wave tile 128x64), BK=64
// swizzled, double-buffered (2 x 64KB), counted vmcnt(8) pipeline.
// Rows < 2047: GX fp16 (LDS-staged coalesced store in 2 chunks).
// Rows >= 2047: level-11 LSTM cell in-register.
__global__ __launch_bounds__(512) void gemm_gx(
    const u16* __restrict__ xb, const u16* __restrict__ Wp,
    const float* __restrict__ bge, u16* __restrict__ GX,
    u16* __restrict__ hdst, float* __restrict__ cdst)
{
    __shared__ u16 smem[65536];   // 128 KB

    int b = blockIdx.x + 16 * blockIdx.y;   // grid 16x16 = 256 blocks
    const int x = b & 7, t = b >> 3;        // t 0..31
    const int ct = (t & 1) * 8 + x;         // 0..15, ct%8 == XCD
    const int mt = t >> 1;                  // 0..15
    const int m0 = mt * 256, c0 = ct * 256;

    const int tid = threadIdx.x, lane = tid & 63, w = tid >> 6;
    const int wm = w >> 2, wn = w & 3;      // wave tile: rows wm*128+, cols wn*64+

    f32x4 acc[8][4];
    #pragma unroll
    for (int i = 0; i < 8; ++i)
        #pragma unroll
        for (int j = 0; j < 4; ++j)
            acc[i][j] = f32x4{0.f, 0.f, 0.f, 0.f};

    // staging: 4096 slots x 16B per tile; slot s: row s>>3 (A r<256, B r-256),
    // byte (s&7)*16 within the 128B row; source element pre-swizzled.
    u16* bufs[2] = {smem, smem + 32768};
    const u16* gp[8];
    u16* dl0[8];
    u16* dl1[8];
    #pragma unroll
    for (int i = 0; i < 8; ++i) {
        const int s = tid + i * 512;
        const int r = s >> 3;
        const int o = (s & 7) * 16;
        const int ke = (o ^ ((r & 7) << 4)) >> 1;   // element offset 0..63
        gp[i] = (r < 256) ? xb + (size_t)(m0 + r) * 1024 + ke
                          : Wp + (size_t)(c0 + r - 256) * 1024 + ke;
        dl0[i] = bufs[0] + s * 8;
        dl1[i] = bufs[1] + s * 8;
    }

    const int fl = lane & 15;
    const int kunit = (lane >> 4) * 16;   // byte offset of fragment in row

    #define STAGE0() { _Pragma("unroll") \
        for (int i = 0; i < 8; ++i) { gload16(gp[i], dl0[i]); gp[i] += 64; } }
    #define STAGE1() { _Pragma("unroll") \
        for (int i = 0; i < 8; ++i) { gload16(gp[i], dl1[i]); gp[i] += 64; } }

    #define COMPUTE(BUF) {                                                   \
        const u16* bA_ = (BUF);                                              \
        const u16* bB_ = (BUF) + 16384;                                      \
        _Pragma("unroll")                                                    \
        for (int ks = 0; ks < 2; ++ks) {                                     \
            bf16x8 a_[8], b_[4];                                             \
            _Pragma("unroll")                                                \
            for (int mi = 0; mi < 8; ++mi) {                                 \
                const int ar = wm * 128 + mi * 16 + fl;                      \
                const int byo = (ks * 64 + kunit) ^ ((ar & 7) << 4);         \
                a_[mi] = *reinterpret_cast<const bf16x8*>(                   \
                    reinterpret_cast<const char*>(bA_ + ar * 64) + byo);     \
            }                                                                \
            _Pragma("unroll")                                                \
            for (int f = 0; f < 4; ++f) {                                    \
                const int br = wn * 64 + f * 16 + fl;                        \
                const int byo = (ks * 64 + kunit) ^ ((br & 7) << 4);         \
                b_[f] = *reinterpret_cast<const bf16x8*>(                    \
                    reinterpret_cast<const char*>(bB_ + br * 64) + byo);     \
            }                                                                \
            _Pragma("unroll")                                                \
            for (int mi = 0; mi < 8; ++mi)                                   \
                _Pragma("unroll")                                            \
                for (int f = 0; f < 4; ++f)                                  \
                    acc[mi][f] = __builtin_amdgcn_mfma_f32_16x16x32_bf16(    \
                        a_[mi], b_[f], acc[mi][f], 0, 0, 0);                 \
        } }

    // 16 K-tiles of 64; prefetch next tile across raw barriers.
    STAGE0();
    #pragma unroll 2
    for (int it = 0; it < 16; ++it) {
        const int cur = it & 1;
        if (it < 15) {
            if (cur == 0) STAGE1() else STAGE0();
            vmwait<8>();
        } else {
            vmwait<0>();
        }
        rbar();
        if (cur == 0) COMPUTE(bufs[0]) else COMPUTE(bufs[1]);
        rbar();
    }
    #undef STAGE0
    #undef STAGE1
    #undef COMPUTE

    const int rg = (lane >> 4) * 4;
    if (m0 < 2047) {
        // stage C (fp16 + bias) in LDS (u16[128][264]) in 2 row-chunks,
        // then coalesced 16B-per-lane stores.
        #pragma unroll
        for (int ch = 0; ch < 2; ++ch) {
            __syncthreads();
            if (wm == ch) {
                #pragma unroll
                for (int mi = 0; mi < 8; ++mi)
                    #pragma unroll
                    for (int f = 0; f < 4; ++f) {
                        const int col = wn * 64 + f * 16 + fl;
                        const float bv = bge[c0 + col];
                        #pragma unroll
                        for (int r = 0; r < 4; ++r)
                            smem[(mi * 16 + rg + r) * 264 + col] =
                                f2h(acc[mi][f][r] + bv);
                    }
            }
            __syncthreads();
            const int row = tid >> 2;            // 0..127
            const int cb = (tid & 3) * 64;       // col base
            const int gm = m0 + ch * 128 + row;
            if (gm < 2047) {
                #pragma unroll
                for (int q = 0; q < 8; ++q) {
                    u16x8 v = *reinterpret_cast<const u16x8*>(
                        &smem[row * 264 + cb + q * 8]);
                    __builtin_nontemporal_store(
                        v, (u16x8*)(GX + (size_t)gm * 4096 + c0 + cb + q * 8));
                }
            }
        }
    }
    if (m0 + 255 >= 2047) {
        // level-11 LSTM cell: c_prev = 0, f-gate unused.
        const int jj = ((c0 + wn * 64) >> 6) * 16 + fl;
        const float bi  = bge[c0 + wn * 64 + fl];
        const float bgg = bge[c0 + wn * 64 + 32 + fl];
        const float bo  = bge[c0 + wn * 64 + 48 + fl];
        #pragma unroll
        for (int mi = 0; mi < 8; ++mi) {
            #pragma unroll
            for (int r = 0; r < 4; ++r) {
                const int m = m0 + wm * 128 + mi * 16 + rg + r;
                if (m < 2047 || m >= 4095) continue;
                const int mm = m - 2047;
                const float cn = fsig(acc[mi][0][r] + bi) * ftanh(acc[mi][2][r] + bgg);
                const float hn = fsig(acc[mi][3][r] + bo) * ftanh(cn);
                hdst[(size_t)(mm >> 1) * 2048 + (mm & 1) * 1024 + jj] = f2bf(hn);
                if (!(mm & 1))
                    cdst[(size_t)(mm >> 1) * 1024 + jj] = cn;
            }
        }
    }
}

// ---------------------------------------------------------------- fused level
// gates = A(h_cat) @ Whh_p^T + GX[node]; K=2048 split KG ways in-block.
// BK=64, both-sides-swizzled LDS (r16-proven, unchanged).
template <int MI, int MW, int NW, int KG>
__global__ __launch_bounds__(MW* NW* KG * 64) void fused_level(
    const u16* __restrict__ A, const u16* __restrict__ Wp,
    const u16* __restrict__ GXl, const float* __restrict__ cprev,
    u16* __restrict__ hnext, float* __restrict__ cnext,
    float* __restrict__ outp, int n)
{
    constexpr int BM = MI * 16 * MW;
    constexpr int BN = NW * 64;
    constexpr int S = MW * NW;
    constexpr int NFR = MI * 4;
    constexpr int RC = NFR > 8 ? 8 : NFR;
    constexpr int NP = NFR / RC;
    constexpr int ROWS = BM + BN;
    constexpr int SLOTS = ROWS * 8;       // 16B slots per BK=64 step
    constexpr int GT = S * 64;
    constexpr int NL = SLOTS / GT;
    static_assert(SLOTS % GT == 0, "slot mapping must be exact");
    constexpr int STG = KG * ROWS * 128;
    constexpr int REDB = (KG > 1) ? (KG - 1) * S * RC * 64 * 16 : 0;
    constexpr int SMEM = STG > REDB ? STG : REDB;
    __shared__ __align__(16) char smem[SMEM];

    const int gx_ = gridDim.x;
    int b = blockIdx.x + gx_ * blockIdx.y;
    const int x = b & 7;
    int t = b >> 3;
    int ct, mt;
    if constexpr (NW == 2) {
        ct = (t & 3) * 8 + x; mt = t >> 2;
    } else {
        const int lo = t & 1; t >>= 1;
        ct = ((t & 3) * 8 + x) * 2 + lo; mt = t >> 2;
    }
    const int m0 = mt * BM;
    const int c0 = ct * BN;

    const int tid = threadIdx.x;
    const int lane = tid & 63;
    const int w = tid >> 6;
    const int kg = w / S;
    const int slot = w % S;
    const int wm = slot / NW;
    const int wn = slot % NW;

    const int Kc = 2048 / KG;
    const int kbeg = kg * Kc;

    u16* buf = (u16*)smem + (size_t)kg * ROWS * 64;

    const int gtid = slot * 64 + lane;
    const u16* gp[NL];
    u16* dl[NL];
    #pragma unroll
    for (int i = 0; i < NL; ++i) {
        const int s = gtid + i * GT;
        const int r = s >> 3;
        const int o = (s & 7) * 16;
        const int ke = (o ^ ((r & 7) << 4)) >> 1;   // element 0..63
        if (r < BM) {
            int ar = m0 + r;
            if (ar >= n) ar = n - 1;
            gp[i] = A + (size_t)ar * 2048 + kbeg + ke;
        } else {
            gp[i] = Wp + (size_t)(c0 + r - BM) * 2048 + kbeg + ke;
        }
        dl[i] = buf + s * 8;
    }

    f32x4 acc[MI][4];
    #pragma unroll
    for (int mi = 0; mi < MI; ++mi)
        #pragma unroll
        for (int f = 0; f < 4; ++f)
            acc[mi][f] = f32x4{0.f, 0.f, 0.f, 0.f};

    const int fl = lane & 15;
    const int kunit = (lane >> 4) * 16;
    const int ar0 = wm * MI * 16;
    const int bc0 = BM;

    for (int k0 = 0; k0 < Kc; k0 += 64) {
        #pragma unroll
        for (int i = 0; i < NL; ++i) { gload16(gp[i], dl[i]); gp[i] += 64; }
        __syncthreads();
        #pragma unroll
        for (int ks = 0; ks < 2; ++ks) {
            bf16x8 a_[MI], b_[4];
            #pragma unroll
            for (int mi = 0; mi < MI; ++mi) {
                const int ar = ar0 + mi * 16 + fl;
                const int byo = (ks * 64 + kunit) ^ ((ar & 7) << 4);
                a_[mi] = *reinterpret_cast<const bf16x8*>(
                    reinterpret_cast<const char*>(buf + ar * 64) + byo);
            }
            #pragma unroll
            for (int f = 0; f < 4; ++f) {
                const int br = bc0 + wn * 64 + f * 16 + fl;
                const int byo = (ks * 64 + kunit) ^ ((br & 7) << 4);
                b_[f] = *reinterpret_cast<const bf16x8*>(
                    reinterpret_cast<const char*>(buf + br * 64) + byo);
            }
            #pragma unroll
            for (int mi = 0; mi < MI; ++mi)
                #pragma unroll
                for (int f = 0; f < 4; ++f)
                    acc[mi][f] = __builtin_amdgcn_mfma_f32_16x16x32_bf16(
                        a_[mi], b_[f], acc[mi][f], 0, 0, 0);
        }
        __syncthreads();
    }

    if constexpr (KG > 1) {
        f32x4* red = reinterpret_cast<f32x4*>(smem);
        #pragma unroll
        for (int pass = 0; pass < NP; ++pass) {
            if (kg > 0) {
                #pragma unroll
                for (int f = 0; f < RC; ++f) {
                    const int fr = pass * RC + f;
                    red[(((kg - 1) * S + slot) * RC + f) * 64 + lane] =
                        acc[fr >> 2][fr & 3];
                }
            }
            __syncthreads();
            if (kg == 0) {
                #pragma unroll
                for (int q = 1; q < KG; ++q)
                    #pragma unroll
                    for (int f = 0; f < RC; ++f) {
                        const int fr = pass * RC + f;
                        f32x4 v = red[(((q - 1) * S + slot) * RC + f) * 64 + lane];
                        acc[fr >> 2][fr & 3][0] += v[0];
                        acc[fr >> 2][fr & 3][1] += v[1];
                        acc[fr >> 2][fr & 3][2] += v[2];
                        acc[fr >> 2][fr & 3][3] += v[3];
                    }
            }
            __syncthreads();
        }
    }

    if (kg != 0) return;
    const int j = ((c0 + wn * 64) >> 6) * 16 + fl;
    #pragma unroll
    for (int mi = 0; mi < MI; ++mi) {
        #pragma unroll
        for (int r = 0; r < 4; ++r) {
            const int m = m0 + wm * MI * 16 + mi * 16 + (lane >> 4) * 4 + r;
            if (m >= n) continue;
            const u16* gx = GXl + (size_t)m * 4096 + c0 + wn * 64 + fl;
            const float i_ = acc[mi][0][r] + h2f(__builtin_nontemporal_load(gx));
            const float f_ = acc[mi][1][r] + h2f(__builtin_nontemporal_load(gx + 16));
            const float g_ = acc[mi][2][r] + h2f(__builtin_nontemporal_load(gx + 32));
            const float o_ = acc[mi][3][r] + h2f(__builtin_nontemporal_load(gx + 48));
            const float cc = __builtin_nontemporal_load(cprev + (size_t)m * 1024 + j);
            const float cn = fsig(f_) * cc + fsig(i_) * ftanh(g_);
            const float hn = fsig(o_) * ftanh(cn);
            if (hnext)
                hnext[(size_t)(m >> 1) * 2048 + (m & 1) * 1024 + j] = f2bf(hn);
            if (!(m & 1))
                __builtin_nontemporal_store(cn, cnext + (size_t)(m >> 1) * 1024 + j);
            if (outp) { outp[j] = hn; outp[1024 + j] = cn; }
        }
    }
}

// ---------------------------------------------------------------- launcher
extern "C" void kernel_launch(void* const* d_in, const int* in_sizes, int n_in,
                              void* d_out, int out_size, void* d_ws, size_t ws_size,
                              hipStream_t stream) {
    const float* emb  = (const float*)d_in[0];
    const float* W_ih = (const float*)d_in[1];
    const float* W_hh = (const float*)d_in[2];
    const float* b_ih = (const float*)d_in[3];
    const float* b_hh = (const float*)d_in[4];
    float* out = (float*)d_out;

    char* p = (char*)d_ws;
    float* bge  = (float*)p;  p += 16384;
    u16* Wih_p  = (u16*)p;    p += (size_t)4096 * 1024 * 2;   //  8.4 MB
    u16* Whh_p  = (u16*)p;    p += (size_t)4096 * 2048 * 2;   // 16.8 MB
    u16* xb     = (u16*)p;    p += (size_t)4096 * 1024 * 2;   //  8.4 MB
    u16* GX     = (u16*)p;    p += (size_t)4096 * 4096 * 2;   // 33.6 MB (rows<2047 used)
    u16* Hcat   = (u16*)p;    p += (size_t)4096 * 2048 * 2;   // 16.8 MB
    float* cbA  = (float*)p;  p += (size_t)1024 * 1024 * 4;   //  4.2 MB
    float* cbB  = (float*)p;  p += (size_t)1024 * 1024 * 4;   //  4.2 MB

    prep<<<16399, 256, 0, stream>>>(W_ih, W_hh, emb, b_ih, b_hh,
                                    Wih_p, Whh_p, xb, bge);

    #define OFF(k) (4096 - (2 << (k)))

    // GX (rows < 2047) + fused level-11 cell (rows >= 2047): 256 blocks.
    gemm_gx<<<dim3(16, 16), 512, 0, stream>>>(
        xb, Wih_p, bge, GX, Hcat + (size_t)OFF(10) * 2048, cbA);

    const float* cprev = cbA;
    float* cbufs[2] = {cbB, cbA};
    int t = 0;
    for (int k = TREE_DEPTH - 2; k >= 0; --k) {
        const int n = 1 << k;
        const u16* A = Hcat + (size_t)OFF(k) * 2048;
        const u16* GXl = GX + (size_t)(n - 1) * 4096;
        u16* hnext = (k > 0) ? (Hcat + (size_t)OFF(k - 1) * 2048) : nullptr;
        float* cnext = cbufs[t];
        float* outp = (k == 0) ? out : nullptr;

        if (k == 10) {
            // BM=64, BN=128, KG=2, 256 thr: 512 blocks (2/CU).
            fused_level<4, 1, 2, 2><<<dim3(16, 32), 256, 0, stream>>>(
                A, Whh_p, GXl, cprev, hnext, cnext, outp, n);
        } else if (k == 9) {
            // BM=32, BN=128, KG=2, 256 thr: 512 blocks (2/CU).
            fused_level<2, 1, 2, 2><<<dim3(16, 32), 256, 0, stream>>>(
                A, Whh_p, GXl, cprev, hnext, cnext, outp, n);
        } else if (k == 8) {
            // BM=16, BN=64, KG=4, 256 thr: 1024 blocks (4/CU).
            fused_level<1, 1, 1, 4><<<dim3(16, 64), 256, 0, stream>>>(
                A, Whh_p, GXl, cprev, hnext, cnext, outp, n);
        } else {
            // BM=16, BN=64, KG=8, 512 thr: up to 512 blocks.
            const int gx = (n >= 16) ? n / 16 : 1;
            fused_level<1, 1, 1, 8><<<dim3(gx, 64), 512, 0, stream>>>(
                A, Whh_p, GXl, cprev, hnext, cnext, outp, n);
        }
        cprev = cnext; t ^= 1;
    }
}

// Round 19
// 221.515 us; speedup vs baseline: 1.0604x; 1.0604x over previous
//
#include <hip/hip_runtime.h>
#include <hip/hip_bf16.h>
#include <math.h>

// BinaryTreeLSTM — round 19: revert gemm_gx to r16-proven form (r18's 256^2
// regressed: 1 blk/CU + C-store write-amp). NEW: tail levels k<=5 get
// cross-block K-split (KSX) so all 256 CUs stream the 16.8MB weight set
// (was 64-128 blocks = BW-starved); partial slabs + act_tail epilogue.
//
// Packed gate-interleaved column space: e = (j/16)*64 + g*16 + (j%16)
//   (orig W row g*2048+j). Wih_p[4096][1024], Whh_p[4096][2048] bf16,
//   XCD-affine 128-row tiles.
// GX[4096][4096] fp16: rows 0..2046 = bf16(emb[node]) @ Wih_p^T + bge;
//   rows >= 2047 (level-11) consumed in-register by the gemm_gx epilogue.
// Hcat: level-k h-slab at row OFF(k)=4096-2^(k+1), 2^k rows x 2048 bf16.
// c compact: level k writes even-node c at row m>>1 (1024 f32); k-1 reads row m.

#define TREE_DEPTH 12

typedef unsigned short u16;
typedef unsigned int u32;
typedef __attribute__((ext_vector_type(8))) short bf16x8;
typedef __attribute__((ext_vector_type(4))) float f32x4;
typedef __attribute__((ext_vector_type(8))) unsigned short u16x8;
typedef __attribute__((ext_vector_type(2))) unsigned int u32x2;

__device__ __forceinline__ void gload16(const void* g, void* l) {
    __builtin_amdgcn_global_load_lds(
        (const __attribute__((address_space(1))) u32*)g,
        (__attribute__((address_space(3))) u32*)l, 16, 0, 0);
}

__device__ __forceinline__ u16 f2bf(float f) {
    __hip_bfloat16 h = __float2bfloat16(f);
    return *reinterpret_cast<u16*>(&h);
}
__device__ __forceinline__ u16 f2h(float f) {
    _Float16 h = (_Float16)f;
    return *reinterpret_cast<u16*>(&h);
}
__device__ __forceinline__ float h2f(u16 u) {
    _Float16 h;
    *reinterpret_cast<u16*>(&h) = u;
    return (float)h;
}
__device__ __forceinline__ float fsig(float x) {
    return 1.0f / (1.0f + __expf(-x));
}
__device__ __forceinline__ float ftanh(float x) {
    return 1.0f - 2.0f / (1.0f + __expf(2.0f * x));
}

// ---------------------------------------------------------------- prep
__global__ void prep(const float* __restrict__ Wih,
                     const float* __restrict__ Whh,
                     const float* __restrict__ emb,
                     const float* __restrict__ b_ih,
                     const float* __restrict__ b_hh,
                     u16* __restrict__ Wih_p, u16* __restrict__ Whh_p,
                     u16* __restrict__ xb, float* __restrict__ bge) {
    const int bid = blockIdx.x;
    if (bid < 12288) {
        const int b = bid & 4095;
        const int seg = bid >> 12;         // 0: ih, 1/2: hh halves
        const int x = b & 7, t = b >> 3;   // t in [0,512)
        const int e = ((t & 3) * 8 + x) * 128 + (t >> 2);  // (e>>7)%8 == x
        const int g = (e >> 4) & 3;
        const int j = (e >> 6) * 16 + (e & 15);
        const int wr = g * 2048 + j;
        const int col = threadIdx.x * 4;
        f32x4 v;
        u16* dst;
        if (seg == 0) {
            v = __builtin_nontemporal_load(
                (const f32x4*)(Wih + (size_t)wr * 1024 + col));
            dst = Wih_p + (size_t)e * 1024 + col;
        } else {
            v = __builtin_nontemporal_load(
                (const f32x4*)(Whh + (size_t)wr * 2048 + (seg - 1) * 1024 + col));
            dst = Whh_p + (size_t)e * 2048 + (seg - 1) * 1024 + col;
        }
        u32x2 p;
        p[0] = (u32)f2bf(v[0]) | ((u32)f2bf(v[1]) << 16);
        p[1] = (u32)f2bf(v[2]) | ((u32)f2bf(v[3]) << 16);
        *reinterpret_cast<u32x2*>(dst) = p;
    } else if (bid < 16383) {
        size_t idx = ((size_t)(bid - 12288) * 256 + threadIdx.x) * 4;
        f32x4 v = __builtin_nontemporal_load((const f32x4*)(emb + idx));
        u32x2 p;
        p[0] = (u32)f2bf(v[0]) | ((u32)f2bf(v[1]) << 16);
        p[1] = (u32)f2bf(v[2]) | ((u32)f2bf(v[3]) << 16);
        *reinterpret_cast<u32x2*>(xb + idx) = p;
    } else {
        int e = (bid - 16383) * 256 + threadIdx.x;   // 0..4095 packed order
        int g = (e >> 4) & 3;
        int j = (e >> 6) * 16 + (e & 15);
        int r = g * 2048 + j;
        bge[e] = b_ih[r] + b_hh[r];
    }
}

// ---------------------------------------------------------------- GX GEMM
// r16-proven: 128x128 tile, 4 waves, BK=64 single-buffer, both-sides swizzle.
// Rows < 2047: GX fp16 (LDS-staged coalesced store). Rows >= 2047: L11 cell.
__global__ __launch_bounds__(256) void gemm_gx(
    const u16* __restrict__ xb, const u16* __restrict__ Wp,
    const float* __restrict__ bge, u16* __restrict__ GX,
    u16* __restrict__ hdst, float* __restrict__ cdst)
{
    __shared__ u16 smem[128 * 140];   // staging uses [0, 256*64) u16

    const int gx_ = gridDim.x;   // 32
    int b = blockIdx.x + gx_ * blockIdx.y;
    const int x = b & 7, t = b >> 3;
    const int ct = (t & 3) * 8 + x;
    const int mt = t >> 2;
    const int m0 = mt * 128, c0 = ct * 128;

    const int tid = threadIdx.x, lane = tid & 63, w = tid >> 6;
    const int wr = (w >> 1) * 64, wc = (w & 1) * 64;

    f32x4 acc[4][4];
    #pragma unroll
    for (int i = 0; i < 4; ++i)
        #pragma unroll
        for (int j = 0; j < 4; ++j)
            acc[i][j] = f32x4{0.f, 0.f, 0.f, 0.f};

    const u16* gp[8];
    u16* dl[8];
    #pragma unroll
    for (int i = 0; i < 8; ++i) {
        const int s = tid + i * 256;
        const int r = s >> 3;
        const int o = (s & 7) * 16;
        const int ke = (o ^ ((r & 7) << 4)) >> 1;   // element offset 0..63
        gp[i] = (r < 128) ? xb + (size_t)(m0 + r) * 1024 + ke
                          : Wp + (size_t)(c0 + r - 128) * 1024 + ke;
        dl[i] = smem + s * 8;
    }

    const int fl = lane & 15;
    const int kunit = (lane >> 4) * 16;   // byte offset of fragment in k-chunk

    for (int k0 = 0; k0 < 1024; k0 += 64) {
        #pragma unroll
        for (int i = 0; i < 8; ++i) { gload16(gp[i], dl[i]); gp[i] += 64; }
        __syncthreads();
        #pragma unroll
        for (int ks = 0; ks < 2; ++ks) {
            bf16x8 a_[4], b_[4];
            #pragma unroll
            for (int i = 0; i < 4; ++i) {
                const int ar = wr + i * 16 + fl;
                const int byo = (ks * 64 + kunit) ^ ((ar & 7) << 4);
                a_[i] = *reinterpret_cast<const bf16x8*>(
                    reinterpret_cast<const char*>(smem + ar * 64) + byo);
            }
            #pragma unroll
            for (int j = 0; j < 4; ++j) {
                const int br = 128 + wc + j * 16 + fl;
                const int byo = (ks * 64 + kunit) ^ ((br & 7) << 4);
                b_[j] = *reinterpret_cast<const bf16x8*>(
                    reinterpret_cast<const char*>(smem + br * 64) + byo);
            }
            #pragma unroll
            for (int i = 0; i < 4; ++i)
                #pragma unroll
                for (int j = 0; j < 4; ++j)
                    acc[i][j] = __builtin_amdgcn_mfma_f32_16x16x32_bf16(
                        a_[i], b_[j], acc[i][j], 0, 0, 0);
        }
        __syncthreads();
    }

    const int rg = (lane >> 4) * 4;
    if (m0 < 2047) {
        #pragma unroll
        for (int i = 0; i < 4; ++i)
            #pragma unroll
            for (int j = 0; j < 4; ++j) {
                const float bv = bge[c0 + wc + j * 16 + fl];
                #pragma unroll
                for (int r = 0; r < 4; ++r)
                    smem[(wr + i * 16 + rg + r) * 140 + (wc + j * 16 + fl)] =
                        f2h(acc[i][j][r] + bv);
            }
        __syncthreads();
        const int row_ = tid >> 4, chunk = tid & 15;
        #pragma unroll
        for (int it = 0; it < 8; ++it) {
            const int row = it * 16 + row_;
            if (m0 + row < 2047) {
                u16x8 v = *reinterpret_cast<const u16x8*>(
                    &smem[row * 140 + chunk * 8]);
                __builtin_nontemporal_store(
                    v, (u16x8*)(GX + (size_t)(m0 + row) * 4096 + c0 + chunk * 8));
            }
        }
    }
    if (m0 + 127 >= 2047) {
        const int jj = ((c0 + wc) >> 6) * 16 + fl;
        const float bi  = bge[c0 + wc + fl];
        const float bgg = bge[c0 + wc + 32 + fl];
        const float bo  = bge[c0 + wc + 48 + fl];
        #pragma unroll
        for (int i = 0; i < 4; ++i) {
            #pragma unroll
            for (int r = 0; r < 4; ++r) {
                const int m = m0 + wr + i * 16 + rg + r;
                if (m < 2047 || m >= 4095) continue;
                const int mm = m - 2047;
                const float cn = fsig(acc[i][0][r] + bi) * ftanh(acc[i][2][r] + bgg);
                const float hn = fsig(acc[i][3][r] + bo) * ftanh(cn);
                hdst[(size_t)(mm >> 1) * 2048 + (mm & 1) * 1024 + jj] = f2bf(hn);
                if (!(mm & 1))
                    cdst[(size_t)(mm >> 1) * 1024 + jj] = cn;
            }
        }
    }
}

// ---------------------------------------------------------------- fused level
// gates = A(h_cat) @ Whh_p^T + GX[node]; K split KG ways in-block, and
// (KSX>1) additionally split KSX ways ACROSS blocks (partials + act_tail).
template <int MI, int MW, int NW, int KG, int KSX>
__global__ __launch_bounds__(MW* NW* KG * 64) void fused_level(
    const u16* __restrict__ A, const u16* __restrict__ Wp,
    const u16* __restrict__ GXl, const float* __restrict__ cprev,
    u16* __restrict__ hnext, float* __restrict__ cnext,
    float* __restrict__ outp, int n, float* __restrict__ pout)
{
    constexpr int BM = MI * 16 * MW;
    constexpr int BN = NW * 64;
    constexpr int S = MW * NW;
    constexpr int NFR = MI * 4;
    constexpr int RC = NFR > 8 ? 8 : NFR;
    constexpr int NP = NFR / RC;
    constexpr int ROWS = BM + BN;
    constexpr int SLOTS = ROWS * 8;       // 16B slots per BK=64 step
    constexpr int GT = S * 64;
    constexpr int NL = SLOTS / GT;
    static_assert(SLOTS % GT == 0, "slot mapping must be exact");
    constexpr int STG = KG * ROWS * 128;
    constexpr int REDB = (KG > 1) ? (KG - 1) * S * RC * 64 * 16 : 0;
    constexpr int SMEM = STG > REDB ? STG : REDB;
    __shared__ __align__(16) char smem[SMEM];

    const int gx_ = gridDim.x;
    int b = blockIdx.x + gx_ * blockIdx.y;
    const int x = b & 7;
    int t = b >> 3;
    int ct, mt;
    if constexpr (NW == 2) {
        ct = (t & 3) * 8 + x; mt = t >> 2;
    } else {
        const int lo = t & 1; t >>= 1;
        ct = ((t & 3) * 8 + x) * 2 + lo; mt = t >> 2;
    }
    const int m0 = mt * BM;
    const int c0 = ct * BN;

    const int tid = threadIdx.x;
    const int lane = tid & 63;
    const int w = tid >> 6;
    const int kg = w / S;
    const int slot = w % S;
    const int wm = slot / NW;
    const int wn = slot % NW;

    const int Kc = (2048 / KSX) / KG;
    const int kbeg = (int)blockIdx.z * (2048 / KSX) + kg * Kc;

    u16* buf = (u16*)smem + (size_t)kg * ROWS * 64;

    const int gtid = slot * 64 + lane;
    const u16* gp[NL];
    u16* dl[NL];
    #pragma unroll
    for (int i = 0; i < NL; ++i) {
        const int s = gtid + i * GT;
        const int r = s >> 3;
        const int o = (s & 7) * 16;
        const int ke = (o ^ ((r & 7) << 4)) >> 1;   // element 0..63
        if (r < BM) {
            int ar = m0 + r;
            if (ar >= n) ar = n - 1;
            gp[i] = A + (size_t)ar * 2048 + kbeg + ke;
        } else {
            gp[i] = Wp + (size_t)(c0 + r - BM) * 2048 + kbeg + ke;
        }
        dl[i] = buf + s * 8;
    }

    f32x4 acc[MI][4];
    #pragma unroll
    for (int mi = 0; mi < MI; ++mi)
        #pragma unroll
        for (int f = 0; f < 4; ++f)
            acc[mi][f] = f32x4{0.f, 0.f, 0.f, 0.f};

    const int fl = lane & 15;
    const int kunit = (lane >> 4) * 16;
    const int ar0 = wm * MI * 16;
    const int bc0 = BM;

    for (int k0 = 0; k0 < Kc; k0 += 64) {
        #pragma unroll
        for (int i = 0; i < NL; ++i) { gload16(gp[i], dl[i]); gp[i] += 64; }
        __syncthreads();
        #pragma unroll
        for (int ks = 0; ks < 2; ++ks) {
            bf16x8 a_[MI], b_[4];
            #pragma unroll
            for (int mi = 0; mi < MI; ++mi) {
                const int ar = ar0 + mi * 16 + fl;
                const int byo = (ks * 64 + kunit) ^ ((ar & 7) << 4);
                a_[mi] = *reinterpret_cast<const bf16x8*>(
                    reinterpret_cast<const char*>(buf + ar * 64) + byo);
            }
            #pragma unroll
            for (int f = 0; f < 4; ++f) {
                const int br = bc0 + wn * 64 + f * 16 + fl;
                const int byo = (ks * 64 + kunit) ^ ((br & 7) << 4);
                b_[f] = *reinterpret_cast<const bf16x8*>(
                    reinterpret_cast<const char*>(buf + br * 64) + byo);
            }
            #pragma unroll
            for (int mi = 0; mi < MI; ++mi)
                #pragma unroll
                for (int f = 0; f < 4; ++f)
                    acc[mi][f] = __builtin_amdgcn_mfma_f32_16x16x32_bf16(
                        a_[mi], b_[f], acc[mi][f], 0, 0, 0);
        }
        __syncthreads();
    }

    if constexpr (KG > 1) {
        f32x4* red = reinterpret_cast<f32x4*>(smem);
        #pragma unroll
        for (int pass = 0; pass < NP; ++pass) {
            if (kg > 0) {
                #pragma unroll
                for (int f = 0; f < RC; ++f) {
                    const int fr = pass * RC + f;
                    red[(((kg - 1) * S + slot) * RC + f) * 64 + lane] =
                        acc[fr >> 2][fr & 3];
                }
            }
            __syncthreads();
            if (kg == 0) {
                #pragma unroll
                for (int q = 1; q < KG; ++q)
                    #pragma unroll
                    for (int f = 0; f < RC; ++f) {
                        const int fr = pass * RC + f;
                        f32x4 v = red[(((q - 1) * S + slot) * RC + f) * 64 + lane];
                        acc[fr >> 2][fr & 3][0] += v[0];
                        acc[fr >> 2][fr & 3][1] += v[1];
                        acc[fr >> 2][fr & 3][2] += v[2];
                        acc[fr >> 2][fr & 3][3] += v[3];
                    }
            }
            __syncthreads();
        }
    }

    if (kg != 0) return;

    if constexpr (KSX > 1) {
        // write block-partial (packed-e order) to slab blockIdx.z
        float* po = pout + (size_t)blockIdx.z * n * 4096;
        #pragma unroll
        for (int mi = 0; mi < MI; ++mi)
            #pragma unroll
            for (int f = 0; f < 4; ++f)
                #pragma unroll
                for (int r = 0; r < 4; ++r) {
                    const int m = m0 + wm * MI * 16 + mi * 16 + (lane >> 4) * 4 + r;
                    if (m < n)
                        po[(size_t)m * 4096 + c0 + wn * 64 + f * 16 + fl] =
                            acc[mi][f][r];
                }
        return;
    }

    const int j = ((c0 + wn * 64) >> 6) * 16 + fl;
    #pragma unroll
    for (int mi = 0; mi < MI; ++mi) {
        #pragma unroll
        for (int r = 0; r < 4; ++r) {
            const int m = m0 + wm * MI * 16 + mi * 16 + (lane >> 4) * 4 + r;
            if (m >= n) continue;
            const u16* gx = GXl + (size_t)m * 4096 + c0 + wn * 64 + fl;
            const float i_ = acc[mi][0][r] + h2f(__builtin_nontemporal_load(gx));
            const float f_ = acc[mi][1][r] + h2f(__builtin_nontemporal_load(gx + 16));
            const float g_ = acc[mi][2][r] + h2f(__builtin_nontemporal_load(gx + 32));
            const float o_ = acc[mi][3][r] + h2f(__builtin_nontemporal_load(gx + 48));
            const float cc = __builtin_nontemporal_load(cprev + (size_t)m * 1024 + j);
            const float cn = fsig(f_) * cc + fsig(i_) * ftanh(g_);
            const float hn = fsig(o_) * ftanh(cn);
            if (hnext)
                hnext[(size_t)(m >> 1) * 2048 + (m & 1) * 1024 + j] = f2bf(hn);
            if (!(m & 1))
                __builtin_nontemporal_store(cn, cnext + (size_t)(m >> 1) * 1024 + j);
            if (outp) { outp[j] = hn; outp[1024 + j] = cn; }
        }
    }
}

// ---------------------------------------------------------------- act_tail
// Sums KSX partial slabs (packed-e fp32) + GX (fp16), applies the LSTM cell.
__global__ void act_tail(const float* __restrict__ parts, int ksn, size_t stride,
                         const u16* __restrict__ GXl,
                         const float* __restrict__ cprev,
                         u16* __restrict__ hnext, float* __restrict__ cnext,
                         float* __restrict__ outp, int n)
{
    int idx = blockIdx.x * 256 + threadIdx.x;   // n*256 total
    if (idx >= n * 256) return;
    const int m = idx >> 8;
    const int j4 = (idx & 255) * 4;
    const int eb = (j4 >> 4) * 64 + (j4 & 15);   // base e for gate 0

    const u16* gx = GXl + (size_t)m * 4096;
    float iv[4], fv[4], gv[4], ov[4];
    #pragma unroll
    for (int t = 0; t < 4; ++t) {
        iv[t] = h2f(gx[eb + t]);
        fv[t] = h2f(gx[eb + 16 + t]);
        gv[t] = h2f(gx[eb + 32 + t]);
        ov[t] = h2f(gx[eb + 48 + t]);
    }
    for (int s = 0; s < ksn; ++s) {
        const float* p = parts + (size_t)s * stride + (size_t)m * 4096;
        #pragma unroll
        for (int t = 0; t < 4; ++t) {
            iv[t] += p[eb + t];
            fv[t] += p[eb + 16 + t];
            gv[t] += p[eb + 32 + t];
            ov[t] += p[eb + 48 + t];
        }
    }
    #pragma unroll
    for (int t = 0; t < 4; ++t) {
        const float cc = cprev[(size_t)m * 1024 + j4 + t];
        const float cn = fsig(fv[t]) * cc + fsig(iv[t]) * ftanh(gv[t]);
        const float hn = fsig(ov[t]) * ftanh(cn);
        if (hnext)
            hnext[(size_t)(m >> 1) * 2048 + (m & 1) * 1024 + j4 + t] = f2bf(hn);
        if (!(m & 1))
            cnext[(size_t)(m >> 1) * 1024 + j4 + t] = cn;
        if (outp) { outp[j4 + t] = hn; outp[1024 + j4 + t] = cn; }
    }
}

// ---------------------------------------------------------------- launcher
extern "C" void kernel_launch(void* const* d_in, const int* in_sizes, int n_in,
                              void* d_out, int out_size, void* d_ws, size_t ws_size,
                              hipStream_t stream) {
    const float* emb  = (const float*)d_in[0];
    const float* W_ih = (const float*)d_in[1];
    const float* W_hh = (const float*)d_in[2];
    const float* b_ih = (const float*)d_in[3];
    const float* b_hh = (const float*)d_in[4];
    float* out = (float*)d_out;

    char* p = (char*)d_ws;
    float* bge  = (float*)p;  p += 16384;
    u16* Wih_p  = (u16*)p;    p += (size_t)4096 * 1024 * 2;   //  8.4 MB
    u16* Whh_p  = (u16*)p;    p += (size_t)4096 * 2048 * 2;   // 16.8 MB
    u16* xb     = (u16*)p;    p += (size_t)4096 * 1024 * 2;   //  8.4 MB
    u16* GX     = (u16*)p;    p += (size_t)4096 * 4096 * 2;   // 33.6 MB (rows<2047 used)
    u16* Hcat   = (u16*)p;    p += (size_t)4096 * 2048 * 2;   // 16.8 MB
    float* cbA  = (float*)p;  p += (size_t)1024 * 1024 * 4;   //  4.2 MB
    float* cbB  = (float*)p;  p += (size_t)1024 * 1024 * 4;   //  4.2 MB
    float* parts = (float*)p; p += (size_t)4 * 32 * 4096 * 4; //  2.1 MB

    prep<<<16399, 256, 0, stream>>>(W_ih, W_hh, emb, b_ih, b_hh,
                                    Wih_p, Whh_p, xb, bge);

    #define OFF(k) (4096 - (2 << (k)))

    // GX (rows < 2047) + fused level-11 cell (rows >= 2047).
    gemm_gx<<<dim3(32, 32), 256, 0, stream>>>(
        xb, Wih_p, bge, GX, Hcat + (size_t)OFF(10) * 2048, cbA);

    const float* cprev = cbA;
    float* cbufs[2] = {cbB, cbA};
    int t = 0;
    for (int k = TREE_DEPTH - 2; k >= 0; --k) {
        const int n = 1 << k;
        const u16* A = Hcat + (size_t)OFF(k) * 2048;
        const u16* GXl = GX + (size_t)(n - 1) * 4096;
        u16* hnext = (k > 0) ? (Hcat + (size_t)OFF(k - 1) * 2048) : nullptr;
        float* cnext = cbufs[t];
        float* outp = (k == 0) ? out : nullptr;

        if (k == 10) {
            fused_level<4, 1, 2, 2, 1><<<dim3(16, 32), 256, 0, stream>>>(
                A, Whh_p, GXl, cprev, hnext, cnext, outp, n, nullptr);
        } else if (k == 9) {
            fused_level<2, 1, 2, 2, 1><<<dim3(16, 32), 256, 0, stream>>>(
                A, Whh_p, GXl, cprev, hnext, cnext, outp, n, nullptr);
        } else if (k == 8) {
            fused_level<1, 1, 1, 4, 1><<<dim3(16, 64), 256, 0, stream>>>(
                A, Whh_p, GXl, cprev, hnext, cnext, outp, n, nullptr);
        } else if (k >= 6) {
            // n=128/64: 512/256 blocks already — keep single-dispatch fused.
            const int gxd = n / 16;
            fused_level<1, 1, 1, 8, 1><<<dim3(gxd, 64), 512, 0, stream>>>(
                A, Whh_p, GXl, cprev, hnext, cnext, outp, n, nullptr);
        } else if (k == 5) {
            // n=32: KSX=2 -> 256 blocks; partials + act_tail.
            fused_level<1, 1, 1, 8, 2><<<dim3(2, 64, 2), 512, 0, stream>>>(
                A, Whh_p, nullptr, nullptr, nullptr, nullptr, nullptr, n, parts);
            act_tail<<<n, 256, 0, stream>>>(parts, 2, (size_t)n * 4096,
                                            GXl, cprev, hnext, cnext, outp, n);
        } else {
            // n<=16: KSX=4 -> 256 blocks; partials + act_tail.
            const int gxd = (n >= 16) ? n / 16 : 1;
            fused_level<1, 1, 1, 8, 4><<<dim3(gxd, 64, 4), 512, 0, stream>>>(
                A, Whh_p, nullptr, nullptr, nullptr, nullptr, nullptr, n, parts);
            act_tail<<<n, 256, 0, stream>>>(parts, 4, (size_t)n * 4096,
                                            GXl, cprev, hnext, cnext, outp, n);
        }
        cprev = cnext; t ^= 1;
    }
}